// Round 2
// baseline (368.083 us; speedup 1.0000x reference)
//
#include <hip/hip_runtime.h>

// SAN Subtraction: x[8,64,56,56] fp32, K=7, stride=1, pad=3 (reflect), dil=1
// out[n,c,i*7+j, h*56+w] = x[n,c,h,w] - x[n,c, refl(h+i-3), refl(w+j-3)]
// out shape [8,64,49,3136] = 78.68M fp32 = 314.7 MB  -> store-BW bound.

#define HH 56
#define WW 56
#define KK 7
#define PP 3
#define KK2 49          // K*K
#define LL (HH * WW)    // 3136
#define LL4 (LL / 4)    // 784

typedef float v4f __attribute__((ext_vector_type(4)));  // native vector: OK for nontemporal builtins

__device__ __forceinline__ int refl(int v) {
    // single-bounce reflect (p=3 < 56): -1->1, -2->2, -3->3, 56->54, 57->53, 58->52
    v = (v < 0) ? -v : v;
    return (v >= HH) ? (2 * HH - 2 - v) : v;
}

__global__ __launch_bounds__(256) void san_sub_kernel(
        const float* __restrict__ x, float* __restrict__ out, int total4) {
    int tid = blockIdx.x * blockDim.x + threadIdx.x;
    if (tid >= total4) return;

    // linearization: tid = (plane*49 + k)*784 + l4   (plane = n*64+c)
    int l4    = tid % LL4;
    int rest  = tid / LL4;
    int k     = rest % KK2;
    int plane = rest / KK2;

    int l = l4 * 4;
    int h = l / WW;        // row (w = l % 56 is in {0,4,...,52}: 4 elems same row)
    int w = l - h * WW;
    int i = k / KK;
    int j = k - i * KK;

    const float* xp = x + (long)plane * LL;

    // center: aligned 16B load
    v4f c = *reinterpret_cast<const v4f*>(xp + l);

    // neighbor row (reflected), 4 scalar loads (contiguous in the interior)
    const float* xrow = xp + refl(h + i - PP) * WW;
    int base = w + j - PP;
    v4f nb;
    nb.x = xrow[refl(base + 0)];
    nb.y = xrow[refl(base + 1)];
    nb.z = xrow[refl(base + 2)];
    nb.w = xrow[refl(base + 3)];

    v4f r = c - nb;

    // out offset == tid*4 by construction; non-temporal: don't evict x from L2
    __builtin_nontemporal_store(r, reinterpret_cast<v4f*>(out) + tid);
}

extern "C" void kernel_launch(void* const* d_in, const int* in_sizes, int n_in,
                              void* d_out, int out_size, void* d_ws, size_t ws_size,
                              hipStream_t stream) {
    const float* x = (const float*)d_in[0];
    float* out = (float*)d_out;
    int total4 = out_size / 4;                 // 19,668,992 float4 stores
    int block = 256;
    int grid = (total4 + block - 1) / block;   // 76,832 blocks
    san_sub_kernel<<<grid, block, 0, stream>>>(x, out, total4);
}